// Round 10
// baseline (174.725 us; speedup 1.0000x reference)
//
#include <hip/hip_runtime.h>
#include <hip/hip_bf16.h>

// Round 9: 128x128-tile GEMM (2x2 wave grid) for QKV/fc1/fc2; proj + attn
// unchanged from round 8.  N=8, T=1600 (F=64 x V=25), DIM=216, H=6, HD=36.

#define NHEAD  6
#define TLEN   1600
#define DIMC   216
#define HDIM   36
#define NBATCH 8
#define MROWS  12800
#define QK_SCALE (1.f/6.f)
#define C2EXP 0.24022650695910072f   // 1/(6 ln2)

typedef __attribute__((ext_vector_type(8))) short s16x8;
typedef __attribute__((ext_vector_type(4))) float f32x4;

#define MFMA16(a,b,c) __builtin_amdgcn_mfma_f32_16x16x32_bf16((a),(b),(c),0,0,0)

__device__ __forceinline__ float  bf2f(ushort u){ return __uint_as_float((uint)u << 16); }
__device__ __forceinline__ ushort f2bf(float f){
  uint u = __float_as_uint(f);
  u += 0x7FFFu + ((u >> 16) & 1u);      // RNE
  return (ushort)(u >> 16);
}
__device__ __forceinline__ uint cvtpk_bf16(float lo, float hi){
  uint r;
  asm("v_cvt_pk_bf16_f32 %0, %1, %2" : "=v"(r) : "v"(lo), "v"(hi));
  return r;
}
__device__ __forceinline__ float fexp2(float x){   // raw v_exp_f32 (2^x)
  float r;
  asm("v_exp_f32 %0, %1" : "=v"(r) : "v"(x));
  return r;
}
__device__ __forceinline__ float frcp(float x){    // raw v_rcp_f32
  float r;
  asm("v_rcp_f32 %0, %1" : "=v"(r) : "v"(x));
  return r;
}
__device__ __forceinline__ void glds16(const ushort* g, ushort* l){
  __builtin_amdgcn_global_load_lds(
      (const __attribute__((address_space(1))) void*)g,
      (__attribute__((address_space(3))) void*)l, 16, 0, 0);
}

// ---------------------------------------------------------------------------
// Bias tables: bias_t[6][127] scaled by 1/(6 ln2); bias_h[6][625] RAW.
// ---------------------------------------------------------------------------
__global__ __launch_bounds__(256) void bias_tables_kernel(
    const float* __restrict__ t_w1, const float* __restrict__ t_b1,
    const float* __restrict__ t_w2, const float* __restrict__ t_b2,
    const float* __restrict__ h_w1, const float* __restrict__ h_b1,
    const float* __restrict__ h_w2, const float* __restrict__ h_b2,
    const int*  __restrict__ hop,
    float* __restrict__ bias_t, float* __restrict__ bias_h)
{
  __shared__ float tblh[16][NHEAD];
  int tid = threadIdx.x;
  if (tid < 127) {
    float xi = (float)(tid - 63);
    float acc[NHEAD] = {0.f,0.f,0.f,0.f,0.f,0.f};
    for (int d = 0; d < DIMC; ++d) {
      float r = fmaxf(fmaf(xi, t_w1[d], t_b1[d]), 0.f);
      #pragma unroll
      for (int h = 0; h < NHEAD; ++h) acc[h] = fmaf(r, t_w2[h*DIMC + d], acc[h]);
    }
    #pragma unroll
    for (int h = 0; h < NHEAD; ++h)
      bias_t[h*127 + tid] = (acc[h] + t_b2[h]) * C2EXP;
  }
  if (tid >= 128 && tid < 144) {
    int i = tid - 128;
    float xi = (float)i;
    float acc[NHEAD] = {0.f,0.f,0.f,0.f,0.f,0.f};
    for (int d = 0; d < DIMC; ++d) {
      float r = fmaxf(fmaf(xi, h_w1[d], h_b1[d]), 0.f);
      #pragma unroll
      for (int h = 0; h < NHEAD; ++h) acc[h] = fmaf(r, h_w2[h*DIMC + d], acc[h]);
    }
    #pragma unroll
    for (int h = 0; h < NHEAD; ++h) tblh[i][h] = acc[h] + h_b2[h];   // RAW
  }
  __syncthreads();
  for (int i = tid; i < NHEAD*625; i += 256) {
    int h = i / 625, e = i - h*625;
    bias_h[i] = tblh[hop[e]][h];
  }
}

// ---------------------------------------------------------------------------
// Pad-fill: Q pad cols 36..63 = onehot(vq), K pad cols 36..60 = bh[j][vk]
// ---------------------------------------------------------------------------
__global__ __launch_bounds__(256) void padfill_kernel(
    const float* __restrict__ bh_raw,   // [6][25][25]
    ushort* __restrict__ qb, ushort* __restrict__ kb)
{
  int idx = blockIdx.x*256 + threadIdx.x;
  if (idx >= NBATCH*NHEAD*TLEN) return;
  int nh = idx / TLEN, t = idx - nh*TLEN;
  int h = nh % NHEAD;
  int vk = t % 25;
  size_t row = ((size_t)nh*TLEN + t) << 6;
  ushort4 z = {0,0,0,0};
  #pragma unroll
  for (int i = 0; i < 7; ++i) *(ushort4*)(qb + row + 36 + i*4) = z;
  qb[row + 36 + vk] = 0x3F80;   // 1.0 bf16 at onehot(vq)
  #pragma unroll
  for (int j = 0; j < 25; ++j)
    kb[row + 36 + j] = f2bf(bh_raw[h*625 + j*25 + vk]);
  kb[row + 61] = 0; kb[row + 62] = 0; kb[row + 63] = 0;
}

// ---------------------------------------------------------------------------
// Merged weight convert+pad: qkv 768x224, proj 256x224, fc1 896x224, fc2 256x864
// ---------------------------------------------------------------------------
#define CP_QKV 172032   // 768*224
#define CP_PROJ 229376  // + 256*224
#define CP_FC1 430080   // + 896*224
#define CP_TOT 651264   // + 256*864
__global__ __launch_bounds__(256) void convpad4_kernel(
    const float* __restrict__ qkvw, const float* __restrict__ projw,
    const float* __restrict__ fc1w, const float* __restrict__ fc2w,
    ushort* __restrict__ dq, ushort* __restrict__ dp,
    ushort* __restrict__ d1, ushort* __restrict__ d2)
{
  int idx = blockIdx.x*256 + threadIdx.x;
  if (idx >= CP_TOT) return;
  if (idx < CP_QKV) {
    int n = idx / 224, k = idx - n*224;
    dq[idx] = f2bf((n < 648 && k < 216) ? qkvw[n*216 + k] : 0.f);
  } else if (idx < CP_PROJ) {
    int i = idx - CP_QKV;
    int n = i / 224, k = i - n*224;
    dp[i] = f2bf((n < 216 && k < 216) ? projw[n*216 + k] : 0.f);
  } else if (idx < CP_FC1) {
    int i = idx - CP_PROJ;
    int n = i / 224, k = i - n*224;
    d1[i] = f2bf((n < 864 && k < 216) ? fc1w[n*216 + k] : 0.f);
  } else {
    int i = idx - CP_FC1;
    int n = i / 864, k = i - n*864;
    d2[i] = f2bf((n < 216) ? fc2w[n*864 + k] : 0.f);
  }
}

// ---------------------------------------------------------------------------
// LayerNorm: fp32 in (stride 216) -> bf16 out (stride 224, cols 216..223 = 0)
// ---------------------------------------------------------------------------
__global__ __launch_bounds__(256) void ln_kernel(
    const float* __restrict__ x, const float* __restrict__ w,
    const float* __restrict__ b, ushort* __restrict__ out)
{
  int lane = threadIdx.x & 63;
  int row  = blockIdx.x * 4 + (threadIdx.x >> 6);
  const float* xr = x + (size_t)row * DIMC;
  float v0 = xr[lane];
  float v1 = xr[lane + 64];
  float v2 = xr[lane + 128];
  float v3 = (lane < 24) ? xr[lane + 192] : 0.f;
  float s1 = v0 + v1 + v2 + v3;
  float s2 = v0*v0 + v1*v1 + v2*v2 + v3*v3;
  #pragma unroll
  for (int m = 32; m; m >>= 1) { s1 += __shfl_xor(s1, m); s2 += __shfl_xor(s2, m); }
  float mu  = s1 * (1.f/216.f);
  float var = fmaxf(s2 * (1.f/216.f) - mu*mu, 0.f);
  float rs  = rsqrtf(var + 1e-5f);
  ushort* orow = out + (size_t)row * 224;
  orow[lane]       = f2bf((v0-mu)*rs*w[lane]       + b[lane]);
  orow[lane+64]    = f2bf((v1-mu)*rs*w[lane+64]    + b[lane+64]);
  orow[lane+128]   = f2bf((v2-mu)*rs*w[lane+128]   + b[lane+128]);
  if (lane < 32) {
    float vv = (lane < 24) ? (v3-mu)*rs*w[lane+192] + b[lane+192] : 0.f;
    orow[lane+192] = f2bf(vv);
  }
}

enum { EPI_QKV = 0, EPI_PROJ = 1, EPI_FC1 = 2, EPI_FC2 = 3 };

// ---------------------------------------------------------------------------
// 128x128-tile MFMA GEMM: 4 waves in 2x2, wave owns 64x64 (4x4 fragments).
// Per K-step: 8 ds_read_b128, 16 MFMA, 4 glds16.  Double-buffered.
// ---------------------------------------------------------------------------
template<int EPI>
__global__ __launch_bounds__(256) void gemm128(
    const ushort* __restrict__ A, const ushort* __restrict__ B,
    const float* __restrict__ bias, float* __restrict__ outf,
    ushort* __restrict__ oq, ushort* __restrict__ ok, ushort* __restrict__ ov,
    int N, int K)
{
  __shared__ ushort As[2][128*32];
  __shared__ ushort Bs[2][128*32];

  int tid = threadIdx.x;
  int w = tid >> 6, lane = tid & 63, l15 = lane & 15, g = lane >> 4;
  int wr = w >> 1, wc = w & 1;
  int row0 = blockIdx.x*128, col0 = blockIdx.y*128;
  const int NT = K >> 5;

  f32x4 acc[4][4];
  #pragma unroll
  for (int i = 0; i < 4; ++i)
    #pragma unroll
    for (int j = 0; j < 4; ++j) acc[i][j] = (f32x4){0.f,0.f,0.f,0.f};

  #define STG(buf, t)                                                         \
  {                                                                           \
    int k0 = (t) << 5;                                                        \
    _Pragma("unroll")                                                         \
    for (int p = 0; p < 2; ++p) {                                             \
      int idx = p*256 + tid;                                                  \
      int mf = idx >> 6, kq = (idx >> 4) & 3, r = idx & 15;                   \
      glds16(A + (size_t)(row0 + mf*16 + r)*K + k0 + kq*8,                    \
             &As[buf][(p*256 + w*64)*8]);                                     \
    }                                                                         \
    _Pragma("unroll")                                                         \
    for (int p = 0; p < 2; ++p) {                                             \
      int idx = p*256 + tid;                                                  \
      int mf = idx >> 6, kq = (idx >> 4) & 3, r = idx & 15;                   \
      glds16(B + (size_t)(col0 + mf*16 + r)*K + k0 + kq*8,                    \
             &Bs[buf][(p*256 + w*64)*8]);                                     \
    }                                                                         \
  }

  STG(0, 0)
  __syncthreads();

  for (int t = 0; t < NT; ++t) {
    int buf = t & 1;
    if (t + 1 < NT) STG(buf ^ 1, t + 1)
    s16x8 av[4], bv[4];
    #pragma unroll
    for (int i = 0; i < 4; ++i)
      av[i] = *(const s16x8*)&As[buf][((wr*4 + i)*64 + g*16 + l15)*8];
    #pragma unroll
    for (int j = 0; j < 4; ++j)
      bv[j] = *(const s16x8*)&Bs[buf][((wc*4 + j)*64 + g*16 + l15)*8];
    #pragma unroll
    for (int i = 0; i < 4; ++i)
      #pragma unroll
      for (int j = 0; j < 4; ++j)
        acc[i][j] = MFMA16(av[i], bv[j], acc[i][j]);
    __syncthreads();
  }
  #undef STG

  #pragma unroll
  for (int i = 0; i < 4; ++i) {
    #pragma unroll
    for (int j = 0; j < 4; ++j) {
      int c = col0 + wc*64 + j*16 + l15;
      if (c >= N) continue;
      #pragma unroll
      for (int r = 0; r < 4; ++r) {
        int rr = row0 + wr*64 + i*16 + 4*g + r;
        float v = acc[i][j][r];
        if constexpr (EPI == EPI_QKV) {
          int s = c / DIMC, rem = c - s*DIMC;
          int hh = rem / HDIM, d = rem - hh*HDIM;
          int n = rr / TLEN, t = rr - n*TLEN;
          int nh = n*NHEAD + hh;
          ushort bv16 = f2bf(v);
          if (s == 0)      oq[(((size_t)nh*TLEN + t) << 6) + d] = bv16;
          else if (s == 1) ok[(((size_t)nh*TLEN + t) << 6) + d] = bv16;
          else {
            // V: k-slot permute + XOR swizzle, layout [nh][d][1600]
            int tile = t >> 6, pos = t & 63;
            int ks2 = pos >> 5, kg = (pos >> 2) & 7, r2 = pos & 3;
            int sg = ((kg & 3) << 1) + (kg >> 2);
            int posp = ks2*32 + sg*4 + r2;
            int grs = (posp >> 3) ^ (d & 7);
            ov[((size_t)nh*HDIM + d)*TLEN + tile*64 + grs*8 + (posp & 7)] = bv16;
          }
        } else if constexpr (EPI == EPI_FC1) {
          v += bias[c];
          float y = 0.7978845608f*(v + 0.044715f*v*v*v);
          float e = fexp2(-2.885390082f*y);
          v = v * frcp(1.f + e);
          oq[(size_t)rr*864 + c] = f2bf(v);
        } else { // EPI_FC2
          outf[(size_t)rr*DIMC + c] = v + bias[c] + ((const float*)ov)[0];  // unused
        }
      }
    }
  }
}

// fc2 needs residual; specialize via separate kernel to keep arg list simple
__global__ __launch_bounds__(256) void gemm128_fc2(
    const ushort* __restrict__ A, const ushort* __restrict__ B,
    const float* __restrict__ bias, const float* __restrict__ res,
    float* __restrict__ outf, int N, int K)
{
  __shared__ ushort As[2][128*32];
  __shared__ ushort Bs[2][128*32];

  int tid = threadIdx.x;
  int w = tid >> 6, lane = tid & 63, l15 = lane & 15, g = lane >> 4;
  int wr = w >> 1, wc = w & 1;
  int row0 = blockIdx.x*128, col0 = blockIdx.y*128;
  const int NT = K >> 5;

  f32x4 acc[4][4];
  #pragma unroll
  for (int i = 0; i < 4; ++i)
    #pragma unroll
    for (int j = 0; j < 4; ++j) acc[i][j] = (f32x4){0.f,0.f,0.f,0.f};

  #define STG(buf, t)                                                         \
  {                                                                           \
    int k0 = (t) << 5;                                                        \
    _Pragma("unroll")                                                         \
    for (int p = 0; p < 2; ++p) {                                             \
      int idx = p*256 + tid;                                                  \
      int mf = idx >> 6, kq = (idx >> 4) & 3, r = idx & 15;                   \
      glds16(A + (size_t)(row0 + mf*16 + r)*K + k0 + kq*8,                    \
             &As[buf][(p*256 + w*64)*8]);                                     \
    }                                                                         \
    _Pragma("unroll")                                                         \
    for (int p = 0; p < 2; ++p) {                                             \
      int idx = p*256 + tid;                                                  \
      int mf = idx >> 6, kq = (idx >> 4) & 3, r = idx & 15;                   \
      glds16(B + (size_t)(col0 + mf*16 + r)*K + k0 + kq*8,                    \
             &Bs[buf][(p*256 + w*64)*8]);                                     \
    }                                                                         \
  }

  STG(0, 0)
  __syncthreads();

  for (int t = 0; t < NT; ++t) {
    int buf = t & 1;
    if (t + 1 < NT) STG(buf ^ 1, t + 1)
    s16x8 av[4], bv[4];
    #pragma unroll
    for (int i = 0; i < 4; ++i)
      av[i] = *(const s16x8*)&As[buf][((wr*4 + i)*64 + g*16 + l15)*8];
    #pragma unroll
    for (int j = 0; j < 4; ++j)
      bv[j] = *(const s16x8*)&Bs[buf][((wc*4 + j)*64 + g*16 + l15)*8];
    #pragma unroll
    for (int i = 0; i < 4; ++i)
      #pragma unroll
      for (int j = 0; j < 4; ++j)
        acc[i][j] = MFMA16(av[i], bv[j], acc[i][j]);
    __syncthreads();
  }
  #undef STG

  #pragma unroll
  for (int i = 0; i < 4; ++i) {
    #pragma unroll
    for (int j = 0; j < 4; ++j) {
      int c = col0 + wc*64 + j*16 + l15;
      if (c >= N) continue;
      #pragma unroll
      for (int r = 0; r < 4; ++r) {
        int rr = row0 + wr*64 + i*16 + 4*g + r;
        outf[(size_t)rr*DIMC + c] = acc[i][j][r] + bias[c] + res[(size_t)rr*DIMC + c];
      }
    }
  }
}

// ---------------------------------------------------------------------------
// proj GEMM (round-6 64-wide structure, small shape)
// ---------------------------------------------------------------------------
__global__ __launch_bounds__(256) void gemm_proj(
    const ushort* __restrict__ A, const ushort* __restrict__ B,
    const float* __restrict__ bias, const float* __restrict__ res,
    float* __restrict__ outf, int N, int K)
{
  constexpr int WM = 16, BM = 64, APASS = 1;
  __shared__ ushort As[2][BM*32];
  __shared__ ushort Bs[2][64*32];

  int tid = threadIdx.x;
  int w = tid >> 6, lane = tid & 63, l15 = lane & 15, g = lane >> 4;
  int row0 = blockIdx.x*BM, col0 = blockIdx.y*64;
  const int NT = K >> 5;

  f32x4 acc[4];
  #pragma unroll
  for (int nf = 0; nf < 4; ++nf) acc[nf] = (f32x4){0.f,0.f,0.f,0.f};

  #define STAGE(buf, t)                                                       \
  {                                                                           \
    int k0 = (t) << 5;                                                        \
    _Pragma("unroll")                                                         \
    for (int p = 0; p < APASS; ++p) {                                         \
      int idx = p*256 + tid;                                                  \
      int mf = idx >> 6, kq = (idx >> 4) & 3, r = idx & 15;                   \
      glds16(A + (size_t)(row0 + mf*16 + r)*K + k0 + kq*8,                    \
             &As[buf][(p*256 + w*64)*8]);                                     \
    }                                                                         \
    {                                                                         \
      int kq = (tid >> 4) & 3, r = tid & 15;                                  \
      glds16(B + (size_t)(col0 + w*16 + r)*K + k0 + kq*8,                     \
             &Bs[buf][w*512]);                                                \
    }                                                                         \
  }

  STAGE(0, 0)
  __syncthreads();

  for (int t = 0; t < NT; ++t) {
    int buf = t & 1;
    if (t + 1 < NT) STAGE(buf ^ 1, t + 1)
    s16x8 a = *(const s16x8*)&As[buf][(w*64 + g*16 + l15)*8];
    #pragma unroll
    for (int nf = 0; nf < 4; ++nf) {
      s16x8 b = *(const s16x8*)&Bs[buf][(nf*64 + g*16 + l15)*8];
      acc[nf] = MFMA16(a, b, acc[nf]);
    }
    __syncthreads();
  }
  #undef STAGE

  #pragma unroll
  for (int nf = 0; nf < 4; ++nf) {
    int c = col0 + nf*16 + l15;
    if (c >= N) continue;
    #pragma unroll
    for (int r = 0; r < 4; ++r) {
      int rr = row0 + w*WM + 4*g + r;
      outf[(size_t)rr*DIMC + c] = acc[nf][r] + bias[c] + res[(size_t)rr*DIMC + c];
    }
  }
}

// ---------------------------------------------------------------------------
// Attention (unchanged from round 8)
// ---------------------------------------------------------------------------
__global__ __launch_bounds__(256) void attn_kernel(
    const ushort* __restrict__ qb, const ushort* __restrict__ kb,
    const ushort* __restrict__ vb, const float* __restrict__ bt_g,
    ushort* __restrict__ o)
{
  __shared__ ushort Ks[2][64*64];
  __shared__ ushort Vt[2][48*64];
  __shared__ float bts[128];

  int tid = threadIdx.x;
  int bid = blockIdx.x;
  int c   = bid >> 3;
  int c25 = c / 25;
  int nh  = (bid & 7)*6 + c25;
  int qt  = c - c25*25;
  int head = nh % NHEAD, n = nh / NHEAD;
  int wave = tid >> 6, lane = tid & 63;
  int g = lane >> 4, l15 = lane & 15, l7 = l15 & 7;

  if (tid < 127) bts[tid + 1] = bt_g[head*127 + tid];
  if (tid == 127) bts[0] = 0.f;
  for (int i = tid; i < 768; i += 256) {
    int b = i / 384, j = i - b*384;
    ((uint*)&Vt[b][36*64])[j] = (j < 32) ? 0x3F803F80u : 0u;
  }

  int qglob = qt*64 + wave*16 + l15;
  const ushort* qrow = qb + (((size_t)nh*TLEN + qglob) << 6);
  s16x8 qf0 = *(const s16x8*)(qrow + g*8);
  s16x8 qf1 = *(const s16x8*)(qrow + 32 + g*8);

  int fq = qglob / 25;

  int vkb[4], ftb[4];
  #pragma unroll
  for (int kt = 0; kt < 4; ++kt) {
    int k0 = kt*16 + 4*g;
    int f0 = (k0 >= 50) ? 2 : (k0 >= 25 ? 1 : 0);
    vkb[kt] = k0 - f0*25;
    ftb[kt] = fq - f0 + 64;
  }

  f32x4 oa[3];
  #pragma unroll
  for (int dt = 0; dt < 3; ++dt) oa[dt] = (f32x4){0.f,0.f,0.f,0.f};

  int srow = tid >> 3, sgrl = tid & 7;
  const ushort* kp = kb + ((size_t)nh*TLEN << 6)
                   + (srow << 6) + ((sgrl ^ (srow & 7)) << 3);
  const ushort* vp = vb + (size_t)nh*HDIM*TLEN + srow*TLEN + sgrl*8;

  glds16(kp,        &Ks[0][wave*512]);
  glds16(kp + 2048, &Ks[0][2048 + wave*512]);
  glds16(vp,        &Vt[0][wave*512]);
  if (tid < 32) glds16(vp + 32*TLEN, &Vt[0][2048]);
  kp += 4096; vp += 64;
  __syncthreads();

  for (int t = 0; t < 25; ++t) {
    int buf = t & 1;
    if (t < 24) {
      ushort* kd = &Ks[buf ^ 1][wave*512];
      glds16(kp,        kd);
      glds16(kp + 2048, kd + 2048);
      glds16(vp,        &Vt[buf ^ 1][wave*512]);
      if (tid < 32) glds16(vp + 32*TLEN, &Vt[buf ^ 1][2048]);
      kp += 4096; vp += 64;
    }

    f32x4 sa[4];
    #pragma unroll
    for (int kt = 0; kt < 4; ++kt) {
      const ushort* krow = &Ks[buf][(kt*16 + l15) << 6];
      s16x8 a0 = *(const s16x8*)(krow + ((g ^ l7) << 3));
      s16x8 a1 = *(const s16x8*)(krow + (((g + 4) ^ l7) << 3));
      f32x4 z = (f32x4){0.f,0.f,0.f,0.f};
      z = MFMA16(a0, qf0, z);
      sa[kt] = MFMA16(a1, qf1, z);
    }

    #pragma unroll
    for (int kt = 0; kt < 4; ++kt) {
      float bt0 = bts[ftb[kt]];
      float bt1 = bts[ftb[kt] - 1];
      #pragma unroll
      for (int r = 0; r < 4; ++r) {
        float btv = (vkb[kt] + r >= 25) ? bt1 : bt0;
        sa[kt][r] = fexp2(fmaf(sa[kt][r], C2EXP, btv));
      }
    }

    #pragma unroll
    for (int ks = 0; ks < 2; ++ks) {
      union { s16x8 v; uint u[4]; } pf;
      pf.u[0] = cvtpk_bf16(sa[2*ks][0],   sa[2*ks][1]);
      pf.u[1] = cvtpk_bf16(sa[2*ks][2],   sa[2*ks][3]);
      pf.u[2] = cvtpk_bf16(sa[2*ks+1][0], sa[2*ks+1][1]);
      pf.u[3] = cvtpk_bf16(sa[2*ks+1][2], sa[2*ks+1][3]);
      #pragma unroll
      for (int dt = 0; dt < 3; ++dt) {
        s16x8 a = *(const s16x8*)&Vt[buf][((dt*16 + l15) << 6) +
                                          ((((ks << 2) + g) ^ l7) << 3)];
        oa[dt] = MFMA16(a, pf.v, oa[dt]);
      }
    }

    #pragma unroll
    for (int kt = 0; kt < 4; ++kt) {
      vkb[kt] += 14; ftb[kt] -= 2;
      if (vkb[kt] >= 25) { vkb[kt] -= 25; ftb[kt] -= 1; }
    }

    __syncthreads();
  }

  float ls = (g == 1) ? oa[2][0] : 0.f;
  ls += __shfl_xor(ls, 16);
  ls += __shfl_xor(ls, 32);
  float inv = frcp(ls);
  ushort* orow = o + ((size_t)(n*TLEN + qglob))*224 + head*HDIM;
  #pragma unroll
  for (int dt = 0; dt < 3; ++dt) {
    if (dt < 2 || g == 0) {
      ushort4 st;
      st.x = f2bf(oa[dt][0]*inv);
      st.y = f2bf(oa[dt][1]*inv);
      st.z = f2bf(oa[dt][2]*inv);
      st.w = f2bf(oa[dt][3]*inv);
      *(ushort4*)(orow + dt*16 + 4*g) = st;
    }
  }
}

// ---------------------------------------------------------------------------
extern "C" void kernel_launch(void* const* d_in, const int* in_sizes, int n_in,
                              void* d_out, int out_size, void* d_ws, size_t ws_size,
                              hipStream_t stream) {
  const float* x      = (const float*)d_in[0];
  const float* qkv_w  = (const float*)d_in[1];
  const float* proj_w = (const float*)d_in[2];
  const float* proj_b = (const float*)d_in[3];
  const float* norm_w = (const float*)d_in[4];
  const float* norm_b = (const float*)d_in[5];
  const float* norm1_w= (const float*)d_in[6];
  const float* norm1_b= (const float*)d_in[7];
  const float* fc1_w  = (const float*)d_in[8];
  const float* fc1_b  = (const float*)d_in[9];
  const float* fc2_w  = (const float*)d_in[10];
  const float* fc2_b  = (const float*)d_in[11];
  const float* t_w1   = (const float*)d_in[12];
  const float* t_b1   = (const float*)d_in[13];
  const float* t_w2   = (const float*)d_in[14];
  const float* t_b2   = (const float*)d_in[15];
  const float* h_w1   = (const float*)d_in[16];
  const float* h_b1   = (const float*)d_in[17];
  const float* h_w2   = (const float*)d_in[18];
  const float* h_b2   = (const float*)d_in[19];
  const int*   hop    = (const int*)d_in[20];

  const size_t WS_NEED = 40627840u;
  if (ws_size < WS_NEED) return;

  char* ws = (char*)d_ws;
  ushort* h_bf   = (ushort*)(ws);
  ushort* q_bf   = (ushort*)(ws + 5734400);
  ushort* k_bf   = (ushort*)(ws + 15564800);
  ushort* v_bf   = (ushort*)(ws + 25395200);
  ushort* o_bf   = (ushort*)(ws + 30924800);
  float*  x1     = (float*) (ws);
  ushort* h1_bf  = (ushort*)(ws + 11468800);
  ushort* g_bf   = (ushort*)(ws + 17203200);
  ushort* qkv_wb = (ushort*)(ws + 39321600);           // 768*224
  ushort* proj_wb= (ushort*)(ws + 39665664);           // 256*224
  ushort* fc1_wb = (ushort*)(ws + 39780352);           // 896*224
  ushort* fc2_wb = (ushort*)(ws + 40181760);           // 256*864
  float*  bt     = (float*) (ws + 40624128);
  float*  bh     = bt + 127*6;

  (void)hipMemsetAsync(ws + 30924800, 0, 5734400, stream);   // o pad cols only

  bias_tables_kernel<<<1, 256, 0, stream>>>(t_w1, t_b1, t_w2, t_b2,
                                            h_w1, h_b1, h_w2, h_b2, hop, bt, bh);

  padfill_kernel<<<(NBATCH*NHEAD*TLEN + 255)/256, 256, 0, stream>>>(bh, q_bf, k_bf);

  convpad4_kernel<<<(CP_TOT + 255)/256, 256, 0, stream>>>(
      qkv_w, proj_w, fc1_w, fc2_w, qkv_wb, proj_wb, fc1_wb, fc2_wb);

  ln_kernel<<<MROWS/4, 256, 0, stream>>>(x, norm_w, norm_b, h_bf);

  gemm128<EPI_QKV><<<dim3(MROWS/128, 6), 256, 0, stream>>>(
      h_bf, qkv_wb, nullptr, nullptr, q_bf, k_bf, v_bf, 648, 224);

  attn_kernel<<<1200, 256, 0, stream>>>(q_bf, k_bf, v_bf, bt, o_bf);

  gemm_proj<<<dim3(MROWS/64, 4), 256, 0, stream>>>(
      o_bf, proj_wb, proj_b, x, x1, 216, 224);

  ln_kernel<<<MROWS/4, 256, 0, stream>>>(x1, norm1_w, norm1_b, h1_bf);

  gemm128<EPI_FC1><<<dim3(MROWS/128, 7), 256, 0, stream>>>(
      h1_bf, fc1_wb, fc1_b, nullptr, g_bf, nullptr, nullptr, 864, 224);

  gemm128_fc2<<<dim3(MROWS/128, 2), 256, 0, stream>>>(
      g_bf, fc2_wb, fc2_b, x1, (float*)d_out, 216, 864);
}

// Round 11
// 158.733 us; speedup vs baseline: 1.1008x; 1.1008x over previous
//
#include <hip/hip_runtime.h>
#include <hip/hip_bf16.h>

// Round 10: revert GEMMs to round-8 winner (165.1us config); attn LDS trim
// (Vt 48->37 rows), o-pad zeros from attn epilogue (no memset), merged
// padfill+convpad.  N=8, T=1600 (F=64 x V=25), DIM=216, H=6, HD=36.

#define NHEAD  6
#define TLEN   1600
#define DIMC   216
#define HDIM   36
#define NBATCH 8
#define MROWS  12800
#define QK_SCALE (1.f/6.f)
#define C2EXP 0.24022650695910072f   // 1/(6 ln2)

typedef __attribute__((ext_vector_type(8))) short s16x8;
typedef __attribute__((ext_vector_type(4))) float f32x4;

#define MFMA16(a,b,c) __builtin_amdgcn_mfma_f32_16x16x32_bf16((a),(b),(c),0,0,0)

__device__ __forceinline__ float  bf2f(ushort u){ return __uint_as_float((uint)u << 16); }
__device__ __forceinline__ ushort f2bf(float f){
  uint u = __float_as_uint(f);
  u += 0x7FFFu + ((u >> 16) & 1u);      // RNE
  return (ushort)(u >> 16);
}
__device__ __forceinline__ uint cvtpk_bf16(float lo, float hi){
  uint r;
  asm("v_cvt_pk_bf16_f32 %0, %1, %2" : "=v"(r) : "v"(lo), "v"(hi));
  return r;
}
__device__ __forceinline__ float fexp2(float x){   // raw v_exp_f32 (2^x)
  float r;
  asm("v_exp_f32 %0, %1" : "=v"(r) : "v"(x));
  return r;
}
__device__ __forceinline__ float frcp(float x){    // raw v_rcp_f32
  float r;
  asm("v_rcp_f32 %0, %1" : "=v"(r) : "v"(x));
  return r;
}
__device__ __forceinline__ void glds16(const ushort* g, ushort* l){
  __builtin_amdgcn_global_load_lds(
      (const __attribute__((address_space(1))) void*)g,
      (__attribute__((address_space(3))) void*)l, 16, 0, 0);
}

// ---------------------------------------------------------------------------
// Bias tables: bias_t[6][127] scaled by 1/(6 ln2); bias_h[6][625] RAW.
// ---------------------------------------------------------------------------
__global__ __launch_bounds__(256) void bias_tables_kernel(
    const float* __restrict__ t_w1, const float* __restrict__ t_b1,
    const float* __restrict__ t_w2, const float* __restrict__ t_b2,
    const float* __restrict__ h_w1, const float* __restrict__ h_b1,
    const float* __restrict__ h_w2, const float* __restrict__ h_b2,
    const int*  __restrict__ hop,
    float* __restrict__ bias_t, float* __restrict__ bias_h)
{
  __shared__ float tblh[16][NHEAD];
  int tid = threadIdx.x;
  if (tid < 127) {
    float xi = (float)(tid - 63);
    float acc[NHEAD] = {0.f,0.f,0.f,0.f,0.f,0.f};
    for (int d = 0; d < DIMC; ++d) {
      float r = fmaxf(fmaf(xi, t_w1[d], t_b1[d]), 0.f);
      #pragma unroll
      for (int h = 0; h < NHEAD; ++h) acc[h] = fmaf(r, t_w2[h*DIMC + d], acc[h]);
    }
    #pragma unroll
    for (int h = 0; h < NHEAD; ++h)
      bias_t[h*127 + tid] = (acc[h] + t_b2[h]) * C2EXP;
  }
  if (tid >= 128 && tid < 144) {
    int i = tid - 128;
    float xi = (float)i;
    float acc[NHEAD] = {0.f,0.f,0.f,0.f,0.f,0.f};
    for (int d = 0; d < DIMC; ++d) {
      float r = fmaxf(fmaf(xi, h_w1[d], h_b1[d]), 0.f);
      #pragma unroll
      for (int h = 0; h < NHEAD; ++h) acc[h] = fmaf(r, h_w2[h*DIMC + d], acc[h]);
    }
    #pragma unroll
    for (int h = 0; h < NHEAD; ++h) tblh[i][h] = acc[h] + h_b2[h];   // RAW
  }
  __syncthreads();
  for (int i = tid; i < NHEAD*625; i += 256) {
    int h = i / 625, e = i - h*625;
    bias_h[i] = tblh[hop[e]][h];
  }
}

// ---------------------------------------------------------------------------
// Merged pad+convert kernel: 4 weight convpads + Q/K pad-fill in one launch.
// ---------------------------------------------------------------------------
#define CP_QKV 157696   // 704*224
#define CP_PROJ 215040  // + 256*224
#define CP_FC1 415744   // + 896*224
#define CP_TOT 636928   // + 256*864
#define PC_TOT (CP_TOT + NBATCH*NHEAD*TLEN)

__global__ __launch_bounds__(256) void padconv_kernel(
    const float* __restrict__ qkvw, const float* __restrict__ projw,
    const float* __restrict__ fc1w, const float* __restrict__ fc2w,
    ushort* __restrict__ dq, ushort* __restrict__ dp,
    ushort* __restrict__ d1, ushort* __restrict__ d2,
    const float* __restrict__ bh_raw,
    ushort* __restrict__ qb, ushort* __restrict__ kb)
{
  int idx = blockIdx.x*256 + threadIdx.x;
  if (idx < CP_TOT) {
    if (idx < CP_QKV) {
      int n = idx / 224, k = idx - n*224;
      dq[idx] = f2bf((n < 648 && k < 216) ? qkvw[n*216 + k] : 0.f);
    } else if (idx < CP_PROJ) {
      int i = idx - CP_QKV;
      int n = i / 224, k = i - n*224;
      dp[i] = f2bf((n < 216 && k < 216) ? projw[n*216 + k] : 0.f);
    } else if (idx < CP_FC1) {
      int i = idx - CP_PROJ;
      int n = i / 224, k = i - n*224;
      d1[i] = f2bf((n < 864 && k < 216) ? fc1w[n*216 + k] : 0.f);
    } else {
      int i = idx - CP_FC1;
      int n = i / 864, k = i - n*864;
      d2[i] = f2bf((n < 216) ? fc2w[n*864 + k] : 0.f);
    }
    return;
  }
  int i = idx - CP_TOT;
  if (i >= NBATCH*NHEAD*TLEN) return;
  int nh = i / TLEN, t = i - nh*TLEN;
  int h = nh % NHEAD;
  int vk = t % 25;
  size_t row = ((size_t)nh*TLEN + t) << 6;
  ushort4 z = {0,0,0,0};
  #pragma unroll
  for (int j = 0; j < 7; ++j) *(ushort4*)(qb + row + 36 + j*4) = z;
  qb[row + 36 + vk] = 0x3F80;   // 1.0 bf16 at onehot(vq)
  #pragma unroll
  for (int j = 0; j < 25; ++j)
    kb[row + 36 + j] = f2bf(bh_raw[h*625 + j*25 + vk]);
  kb[row + 61] = 0; kb[row + 62] = 0; kb[row + 63] = 0;
}

// ---------------------------------------------------------------------------
// LayerNorm: fp32 in (stride 216) -> bf16 out (stride 224, cols 216..223 = 0)
// ---------------------------------------------------------------------------
__global__ __launch_bounds__(256) void ln_kernel(
    const float* __restrict__ x, const float* __restrict__ w,
    const float* __restrict__ b, ushort* __restrict__ out)
{
  int lane = threadIdx.x & 63;
  int row  = blockIdx.x * 4 + (threadIdx.x >> 6);
  const float* xr = x + (size_t)row * DIMC;
  float v0 = xr[lane];
  float v1 = xr[lane + 64];
  float v2 = xr[lane + 128];
  float v3 = (lane < 24) ? xr[lane + 192] : 0.f;
  float s1 = v0 + v1 + v2 + v3;
  float s2 = v0*v0 + v1*v1 + v2*v2 + v3*v3;
  #pragma unroll
  for (int m = 32; m; m >>= 1) { s1 += __shfl_xor(s1, m); s2 += __shfl_xor(s2, m); }
  float mu  = s1 * (1.f/216.f);
  float var = fmaxf(s2 * (1.f/216.f) - mu*mu, 0.f);
  float rs  = rsqrtf(var + 1e-5f);
  ushort* orow = out + (size_t)row * 224;
  orow[lane]       = f2bf((v0-mu)*rs*w[lane]       + b[lane]);
  orow[lane+64]    = f2bf((v1-mu)*rs*w[lane+64]    + b[lane+64]);
  orow[lane+128]   = f2bf((v2-mu)*rs*w[lane+128]   + b[lane+128]);
  if (lane < 32) {
    float vv = (lane < 24) ? (v3-mu)*rs*w[lane+192] + b[lane+192] : 0.f;
    orow[lane+192] = f2bf(vv);
  }
}

// ---------------------------------------------------------------------------
// MFMA GEMM (round-8 double-buffer structure — best measured)
// ---------------------------------------------------------------------------
enum { EPI_QKV = 0, EPI_PROJ = 1, EPI_FC1 = 2, EPI_FC2 = 3 };

template<int EPI, int WM>
__global__ __launch_bounds__(256) void gemm_mfma(
    const ushort* __restrict__ A, const ushort* __restrict__ B,
    const float* __restrict__ bias, const float* __restrict__ res,
    float* __restrict__ outf, ushort* __restrict__ oq,
    ushort* __restrict__ ok, ushort* __restrict__ ov,
    int N, int K)
{
  constexpr int BM = WM*4;
  constexpr int NMF = WM/16;
  constexpr int APASS = (BM*4)/256;
  __shared__ ushort As[2][BM*32];
  __shared__ ushort Bs[2][64*32];

  int tid = threadIdx.x;
  int w = tid >> 6, lane = tid & 63, l15 = lane & 15, g = lane >> 4;
  int row0 = blockIdx.x*BM, col0 = blockIdx.y*64;
  const int NT = K >> 5;

  f32x4 acc[NMF][4];
  #pragma unroll
  for (int i = 0; i < NMF; ++i)
    #pragma unroll
    for (int nf = 0; nf < 4; ++nf) acc[i][nf] = (f32x4){0.f,0.f,0.f,0.f};

  #define STAGE(buf, t)                                                       \
  {                                                                           \
    int k0 = (t) << 5;                                                        \
    _Pragma("unroll")                                                         \
    for (int p = 0; p < APASS; ++p) {                                         \
      int idx = p*256 + tid;                                                  \
      int mf = idx >> 6, kq = (idx >> 4) & 3, r = idx & 15;                   \
      glds16(A + (size_t)(row0 + mf*16 + r)*K + k0 + kq*8,                    \
             &As[buf][(p*256 + w*64)*8]);                                     \
    }                                                                         \
    {                                                                         \
      int kq = (tid >> 4) & 3, r = tid & 15;                                  \
      glds16(B + (size_t)(col0 + w*16 + r)*K + k0 + kq*8,                     \
             &Bs[buf][w*512]);                                                \
    }                                                                         \
  }

  STAGE(0, 0)
  __syncthreads();

  for (int t = 0; t < NT; ++t) {
    int buf = t & 1;
    if (t + 1 < NT) STAGE(buf ^ 1, t + 1)
    #pragma unroll
    for (int i = 0; i < NMF; ++i) {
      s16x8 a = *(const s16x8*)&As[buf][((w*NMF + i)*64 + g*16 + l15)*8];
      #pragma unroll
      for (int nf = 0; nf < 4; ++nf) {
        s16x8 b = *(const s16x8*)&Bs[buf][(nf*64 + g*16 + l15)*8];
        acc[i][nf] = MFMA16(a, b, acc[i][nf]);
      }
    }
    __syncthreads();
  }
  #undef STAGE

  #pragma unroll
  for (int i = 0; i < NMF; ++i) {
    #pragma unroll
    for (int nf = 0; nf < 4; ++nf) {
      int c = col0 + nf*16 + l15;
      if (c >= N) continue;
      #pragma unroll
      for (int r = 0; r < 4; ++r) {
        int rr = row0 + w*WM + i*16 + 4*g + r;
        float v = acc[i][nf][r];
        if constexpr (EPI == EPI_QKV) {
          int s = c / DIMC, rem = c - s*DIMC;
          int hh = rem / HDIM, d = rem - hh*HDIM;
          int n = rr / TLEN, t = rr - n*TLEN;
          int nh = n*NHEAD + hh;
          ushort bv = f2bf(v);
          if (s == 0)      oq[(((size_t)nh*TLEN + t) << 6) + d] = bv;
          else if (s == 1) ok[(((size_t)nh*TLEN + t) << 6) + d] = bv;
          else {
            // V: k-slot permute + XOR swizzle, layout [nh][d][1600]
            int tile = t >> 6, pos = t & 63;
            int ks2 = pos >> 5, kg = (pos >> 2) & 7, r2 = pos & 3;
            int sg = ((kg & 3) << 1) + (kg >> 2);
            int posp = ks2*32 + sg*4 + r2;
            int grs = (posp >> 3) ^ (d & 7);
            ov[((size_t)nh*HDIM + d)*TLEN + tile*64 + grs*8 + (posp & 7)] = bv;
          }
        } else if constexpr (EPI == EPI_PROJ) {
          outf[(size_t)rr*DIMC + c] = v + bias[c] + res[(size_t)rr*DIMC + c];
        } else if constexpr (EPI == EPI_FC1) {
          v += bias[c];
          // tanh-GELU via raw exp2/rcp (max abs err ~3e-4)
          float y = 0.7978845608f*(v + 0.044715f*v*v*v);
          float e = fexp2(-2.885390082f*y);       // exp(-2y)
          v = v * frcp(1.f + e);
          oq[(size_t)rr*864 + c] = f2bf(v);
        } else {
          outf[(size_t)rr*DIMC + c] = v + bias[c] + res[(size_t)rr*DIMC + c];
        }
      }
    }
  }
}

// ---------------------------------------------------------------------------
// Attention v4: as round 8/9 but Vt trimmed to 37 rows (LDS 29.2K -> 26.4K;
// overreads of rows 37..47 feed only discarded output lanes) and o pad cols
// zeroed by the epilogue (memset launch removed).
// ---------------------------------------------------------------------------
__global__ __launch_bounds__(256) void attn_kernel(
    const ushort* __restrict__ qb, const ushort* __restrict__ kb,
    const ushort* __restrict__ vb, const float* __restrict__ bt_g,
    ushort* __restrict__ o)
{
  __shared__ ushort Ks[2][64*64];
  __shared__ ushort Vt[2][37*64];     // rows 0..35 = V^T, row 36 = ones (lsum)
  __shared__ float bts[128];

  int tid = threadIdx.x;
  int bid = blockIdx.x;
  int c   = bid >> 3;
  int c25 = c / 25;
  int nh  = (bid & 7)*6 + c25;        // XCD r owns batch r's 6 heads
  int qt  = c - c25*25;
  int head = nh % NHEAD, n = nh / NHEAD;
  int wave = tid >> 6, lane = tid & 63;
  int g = lane >> 4, l15 = lane & 15, l7 = l15 & 7;

  if (tid < 127) bts[tid + 1] = bt_g[head*127 + tid];
  if (tid == 127) bts[0] = 0.f;
  if (tid < 64) {                     // ones row d=36, both buffers
    int b = tid >> 5, j = tid & 31;
    ((uint*)&Vt[b][36*64])[j] = 0x3F803F80u;
  }

  int qglob = qt*64 + wave*16 + l15;
  const ushort* qrow = qb + (((size_t)nh*TLEN + qglob) << 6);
  s16x8 qf0 = *(const s16x8*)(qrow + g*8);
  s16x8 qf1 = *(const s16x8*)(qrow + 32 + g*8);

  int fq = qglob / 25;

  int vkb[4], ftb[4];
  #pragma unroll
  for (int kt = 0; kt < 4; ++kt) {
    int k0 = kt*16 + 4*g;
    int f0 = (k0 >= 50) ? 2 : (k0 >= 25 ? 1 : 0);
    vkb[kt] = k0 - f0*25;
    ftb[kt] = fq - f0 + 64;
  }

  f32x4 oa[3];
  #pragma unroll
  for (int dt = 0; dt < 3; ++dt) oa[dt] = (f32x4){0.f,0.f,0.f,0.f};

  int srow = tid >> 3, sgrl = tid & 7;
  const ushort* kp = kb + ((size_t)nh*TLEN << 6)
                   + (srow << 6) + ((sgrl ^ (srow & 7)) << 3);
  const ushort* vp = vb + (size_t)nh*HDIM*TLEN + srow*TLEN + sgrl*8;

  glds16(kp,        &Ks[0][wave*512]);
  glds16(kp + 2048, &Ks[0][2048 + wave*512]);
  glds16(vp,        &Vt[0][wave*512]);
  if (tid < 32) glds16(vp + 32*TLEN, &Vt[0][2048]);
  kp += 4096; vp += 64;
  __syncthreads();

  for (int t = 0; t < 25; ++t) {
    int buf = t & 1;
    if (t < 24) {
      ushort* kd = &Ks[buf ^ 1][wave*512];
      glds16(kp,        kd);
      glds16(kp + 2048, kd + 2048);
      glds16(vp,        &Vt[buf ^ 1][wave*512]);
      if (tid < 32) glds16(vp + 32*TLEN, &Vt[buf ^ 1][2048]);
      kp += 4096; vp += 64;
    }

    f32x4 sa[4];
    #pragma unroll
    for (int kt = 0; kt < 4; ++kt) {
      const ushort* krow = &Ks[buf][(kt*16 + l15) << 6];
      s16x8 a0 = *(const s16x8*)(krow + ((g ^ l7) << 3));
      s16x8 a1 = *(const s16x8*)(krow + (((g + 4) ^ l7) << 3));
      f32x4 z = (f32x4){0.f,0.f,0.f,0.f};
      z = MFMA16(a0, qf0, z);
      sa[kt] = MFMA16(a1, qf1, z);
    }

    #pragma unroll
    for (int kt = 0; kt < 4; ++kt) {
      float bt0 = bts[ftb[kt]];
      float bt1 = bts[ftb[kt] - 1];
      #pragma unroll
      for (int r = 0; r < 4; ++r) {
        float btv = (vkb[kt] + r >= 25) ? bt1 : bt0;
        sa[kt][r] = fexp2(fmaf(sa[kt][r], C2EXP, btv));
      }
    }

    #pragma unroll
    for (int ks = 0; ks < 2; ++ks) {
      union { s16x8 v; uint u[4]; } pf;
      pf.u[0] = cvtpk_bf16(sa[2*ks][0],   sa[2*ks][1]);
      pf.u[1] = cvtpk_bf16(sa[2*ks][2],   sa[2*ks][3]);
      pf.u[2] = cvtpk_bf16(sa[2*ks+1][0], sa[2*ks+1][1]);
      pf.u[3] = cvtpk_bf16(sa[2*ks+1][2], sa[2*ks+1][3]);
      #pragma unroll
      for (int dt = 0; dt < 3; ++dt) {
        s16x8 a = *(const s16x8*)&Vt[buf][((dt*16 + l15) << 6) +
                                          ((((ks << 2) + g) ^ l7) << 3)];
        oa[dt] = MFMA16(a, pf.v, oa[dt]);
      }
    }

    #pragma unroll
    for (int kt = 0; kt < 4; ++kt) {
      vkb[kt] += 14; ftb[kt] -= 2;
      if (vkb[kt] >= 25) { vkb[kt] -= 25; ftb[kt] -= 1; }
    }

    __syncthreads();
  }

  float ls = (g == 1) ? oa[2][0] : 0.f;
  ls += __shfl_xor(ls, 16);
  ls += __shfl_xor(ls, 32);
  float inv = frcp(ls);
  ushort* orow_base = o + ((size_t)(n*TLEN + qglob))*224;
  ushort* orow = orow_base + head*HDIM;
  #pragma unroll
  for (int dt = 0; dt < 3; ++dt) {
    if (dt < 2 || g == 0) {
      ushort4 st;
      st.x = f2bf(oa[dt][0]*inv);
      st.y = f2bf(oa[dt][1]*inv);
      st.z = f2bf(oa[dt][2]*inv);
      st.w = f2bf(oa[dt][3]*inv);
      *(ushort4*)(orow + dt*16 + 4*g) = st;
    }
  }
  if (g >= 2) {                       // zero o pad cols 216..223 (replaces memset)
    ushort4 z = {0,0,0,0};
    *(ushort4*)(orow_base + 216 + (g - 2)*4) = z;
  }
}

// ---------------------------------------------------------------------------
extern "C" void kernel_launch(void* const* d_in, const int* in_sizes, int n_in,
                              void* d_out, int out_size, void* d_ws, size_t ws_size,
                              hipStream_t stream) {
  const float* x      = (const float*)d_in[0];
  const float* qkv_w  = (const float*)d_in[1];
  const float* proj_w = (const float*)d_in[2];
  const float* proj_b = (const float*)d_in[3];
  const float* norm_w = (const float*)d_in[4];
  const float* norm_b = (const float*)d_in[5];
  const float* norm1_w= (const float*)d_in[6];
  const float* norm1_b= (const float*)d_in[7];
  const float* fc1_w  = (const float*)d_in[8];
  const float* fc1_b  = (const float*)d_in[9];
  const float* fc2_w  = (const float*)d_in[10];
  const float* fc2_b  = (const float*)d_in[11];
  const float* t_w1   = (const float*)d_in[12];
  const float* t_b1   = (const float*)d_in[13];
  const float* t_w2   = (const float*)d_in[14];
  const float* t_b2   = (const float*)d_in[15];
  const float* h_w1   = (const float*)d_in[16];
  const float* h_b1   = (const float*)d_in[17];
  const float* h_w2   = (const float*)d_in[18];
  const float* h_b2   = (const float*)d_in[19];
  const int*   hop    = (const int*)d_in[20];

  const size_t WS_NEED = 40613504u;
  if (ws_size < WS_NEED) return;

  char* ws = (char*)d_ws;
  ushort* h_bf   = (ushort*)(ws);
  ushort* q_bf   = (ushort*)(ws + 5734400);
  ushort* k_bf   = (ushort*)(ws + 15564800);
  ushort* v_bf   = (ushort*)(ws + 25395200);
  ushort* o_bf   = (ushort*)(ws + 30924800);
  float*  x1     = (float*) (ws);
  ushort* h1_bf  = (ushort*)(ws + 11468800);
  ushort* g_bf   = (ushort*)(ws + 17203200);
  ushort* qkv_wb = (ushort*)(ws + 39321600);
  ushort* proj_wb= (ushort*)(ws + 39636992);
  ushort* fc1_wb = (ushort*)(ws + 39751680);
  ushort* fc2_wb = (ushort*)(ws + 40153088);
  float*  bt     = (float*) (ws + 40595456);
  float*  bh     = bt + 127*6;

  bias_tables_kernel<<<1, 256, 0, stream>>>(t_w1, t_b1, t_w2, t_b2,
                                            h_w1, h_b1, h_w2, h_b2, hop, bt, bh);

  padconv_kernel<<<(PC_TOT + 255)/256, 256, 0, stream>>>(
      qkv_w, proj_w, fc1_w, fc2_w, qkv_wb, proj_wb, fc1_wb, fc2_wb,
      bh, q_bf, k_bf);

  ln_kernel<<<MROWS/4, 256, 0, stream>>>(x, norm_w, norm_b, h_bf);

  gemm_mfma<EPI_QKV, 32><<<dim3(MROWS/128, 11), 256, 0, stream>>>(
      h_bf, qkv_wb, nullptr, nullptr, nullptr, q_bf, k_bf, v_bf, 648, 224);

  attn_kernel<<<1200, 256, 0, stream>>>(q_bf, k_bf, v_bf, bt, o_bf);

  gemm_mfma<EPI_PROJ, 16><<<dim3(MROWS/64, 4), 256, 0, stream>>>(
      o_bf, proj_wb, proj_b, x, x1, nullptr, nullptr, nullptr, 216, 224);

  ln_kernel<<<MROWS/4, 256, 0, stream>>>(x1, norm1_w, norm1_b, h1_bf);

  gemm_mfma<EPI_FC1, 32><<<dim3(MROWS/128, 14), 256, 0, stream>>>(
      h1_bf, fc1_wb, fc1_b, nullptr, nullptr, g_bf, nullptr, nullptr, 864, 224);

  gemm_mfma<EPI_FC2, 16><<<dim3(MROWS/64, 4), 256, 0, stream>>>(
      g_bf, fc2_wb, fc2_b, x1, (float*)d_out, nullptr, nullptr, nullptr, 216, 864);
}